// Round 10
// baseline (199.257 us; speedup 1.0000x reference)
//
#include <hip/hip_runtime.h>
#include <hip/hip_bf16.h>

#define B 2
#define S 2048
#define D 1024
#define NH 16
#define DH 64
#define M (B*S)
#define BQ 128
#define BK 64
#define KSCALE 0.18033688011112042f   // (1/sqrt(64)) * log2(e) — folded into Qb

typedef __hip_bfloat16 bf16;
typedef __attribute__((ext_vector_type(8))) short frag_ab;   // 8 bf16
typedef __attribute__((ext_vector_type(4))) float frag_cd;   // 4 f32
typedef unsigned long long ull;

// async global->LDS, 16B/lane; LDS dest = wave-uniform base + lane*16
__device__ __forceinline__ void gload_lds16(const bf16* g, bf16* l) {
    __builtin_amdgcn_global_load_lds((const __attribute__((address_space(1))) unsigned int*)g,
                                     (__attribute__((address_space(3))) unsigned int*)l,
                                     16, 0, 0);
}

// ---------- convert x fp32 -> bf16
__global__ __launch_bounds__(256) void cvt_x(const float* __restrict__ x, bf16* __restrict__ xb) {
    const int i = (blockIdx.x * 256 + threadIdx.x) * 4;
    const float4 v = *(const float4*)(x + i);
    __align__(8) bf16 t[4] = {__float2bfloat16(v.x), __float2bfloat16(v.y),
                              __float2bfloat16(v.z), __float2bfloat16(v.w)};
    *(ull*)(xb + i) = *(const ull*)t;
}

// ---------- convert + transpose weights: T[n][k] = W[k][n]
__global__ __launch_bounds__(256) void cvt_wT(const float* __restrict__ W0, const float* __restrict__ W1,
                                              const float* __restrict__ W2, const float* __restrict__ W3,
                                              bf16* __restrict__ T0, bf16* __restrict__ T1,
                                              bf16* __restrict__ T2, bf16* __restrict__ T3) {
    const float* src; bf16* dst;
    switch (blockIdx.z) {
        case 0: src = W0; dst = T0; break;
        case 1: src = W1; dst = T1; break;
        case 2: src = W2; dst = T2; break;
        default: src = W3; dst = T3; break;
    }
    __shared__ float t[32][33];
    const int tx = threadIdx.x & 31, ty = threadIdx.x >> 5;
    const int c0 = blockIdx.x * 32, r0 = blockIdx.y * 32;
#pragma unroll
    for (int i = 0; i < 4; i++)
        t[ty + 8 * i][tx] = src[(size_t)(r0 + ty + 8 * i) * D + c0 + tx];
    __syncthreads();
#pragma unroll
    for (int i = 0; i < 4; i++)
        dst[(size_t)(c0 + ty + 8 * i) * D + r0 + tx] = __float2bfloat16(t[tx][ty + 8 * i]);
}

// ---------- fused QKV GEMM, 64x128 tiles, single-barrier double-buffered K-loop.
// C = xb @ [WqT|WkT|WvT]^T, grid (24,64). Q third row-major PRE-SCALED by KSCALE;
// K third row-major; V third stored TRANSPOSED per head: Vt[bh][d][s].
__global__ __launch_bounds__(256) void gemm_qkv_all(const bf16* __restrict__ A, const bf16* __restrict__ Bt,
                                                    bf16* __restrict__ Qb, bf16* __restrict__ Kb,
                                                    bf16* __restrict__ Vt_g) {
    __shared__ __align__(16) bf16 As[2][64 * BK];    // 8 KB x2
    __shared__ __align__(16) bf16 Bs[2][128 * BK];   // 16 KB x2  => 48 KB total
    const int tid = threadIdx.x, wave = tid >> 6, lane = tid & 63;
    const int r16 = lane & 15, quad = lane >> 4;
    const int row0 = blockIdx.y * 64;
    const int col0 = blockIdx.x * 128;
    const int wm = (wave & 1) * 32, wn = (wave >> 1) * 64;

    frag_cd acc[2][4];
#pragma unroll
    for (int mt = 0; mt < 2; mt++)
#pragma unroll
        for (int nt = 0; nt < 4; nt++) acc[mt][nt] = frag_cd{0.f, 0.f, 0.f, 0.f};

    // prologue: stage k-tile 0 into buf 0
#pragma unroll
    for (int j = 0; j < 2; j++) {
        const int s = wave * 128 + j * 64 + lane;
        const int r = s >> 3, c = (s ^ r) & 7;
        gload_lds16(A + (size_t)(row0 + r) * D + c * 8, &As[0][(wave * 128 + j * 64) * 8]);
    }
#pragma unroll
    for (int j = 0; j < 4; j++) {
        const int s = wave * 256 + j * 64 + lane;
        const int r = s >> 3, c = (s ^ r) & 7;
        gload_lds16(Bt + (size_t)(col0 + r) * D + c * 8, &Bs[0][(wave * 256 + j * 64) * 8]);
    }
    __syncthreads();

    for (int kt = 0; kt < D / BK; kt++) {
        const int cur = kt & 1;
        if (kt + 1 < D / BK) {   // prefetch next tile into alt buffers
            const int kn = (kt + 1) * BK;
#pragma unroll
            for (int j = 0; j < 2; j++) {
                const int s = wave * 128 + j * 64 + lane;
                const int r = s >> 3, c = (s ^ r) & 7;
                gload_lds16(A + (size_t)(row0 + r) * D + kn + c * 8,
                            &As[cur ^ 1][(wave * 128 + j * 64) * 8]);
            }
#pragma unroll
            for (int j = 0; j < 4; j++) {
                const int s = wave * 256 + j * 64 + lane;
                const int r = s >> 3, c = (s ^ r) & 7;
                gload_lds16(Bt + (size_t)(col0 + r) * D + kn + c * 8,
                            &Bs[cur ^ 1][(wave * 256 + j * 64) * 8]);
            }
        }

        frag_ab af[2][2], bf[4][2];
#pragma unroll
        for (int mt = 0; mt < 2; mt++) {
            const int row = wm + mt * 16 + r16;
#pragma unroll
            for (int ks = 0; ks < 2; ks++)
                af[mt][ks] = *(const frag_ab*)&As[cur][row * 64 + (((ks * 4 + quad) ^ (row & 7)) * 8)];
        }
#pragma unroll
        for (int nt = 0; nt < 4; nt++) {
            const int row = wn + nt * 16 + r16;
#pragma unroll
            for (int ks = 0; ks < 2; ks++)
                bf[nt][ks] = *(const frag_ab*)&Bs[cur][row * 64 + (((ks * 4 + quad) ^ (row & 7)) * 8)];
        }
#pragma unroll
        for (int mt = 0; mt < 2; mt++)
#pragma unroll
            for (int nt = 0; nt < 4; nt++)
#pragma unroll
                for (int ks = 0; ks < 2; ks++)
                    acc[mt][nt] = __builtin_amdgcn_mfma_f32_16x16x32_bf16(
                        af[mt][ks], bf[nt][ks], acc[mt][nt], 0, 0, 0);

        __syncthreads();   // prefetch complete + all waves done with cur bufs
    }

    const int third = col0 >> 10;
    if (third < 2) {
        bf16* Out = (third == 0) ? Qb : Kb;
        const float sc = (third == 0) ? KSCALE : 1.f;
#pragma unroll
        for (int mt = 0; mt < 2; mt++)
#pragma unroll
            for (int nt = 0; nt < 4; nt++) {
                const int cl = (col0 + wn + nt * 16 + r16) & 1023;
#pragma unroll
                for (int rg = 0; rg < 4; rg++) {
                    const int row = row0 + wm + mt * 16 + quad * 4 + rg;
                    Out[(size_t)row * D + cl] = __float2bfloat16(acc[mt][nt][rg] * sc);
                }
            }
    } else {
        const int bb = row0 >> 11;
        const int sb0 = (row0 & 2047) + wm;
#pragma unroll
        for (int mt = 0; mt < 2; mt++)
#pragma unroll
            for (int nt = 0; nt < 4; nt++) {
                const int c  = (col0 + wn + nt * 16 + r16) - 2048;
                const int hh = c >> 6, dl = c & 63;
                const int sb = sb0 + mt * 16 + quad * 4;
                __align__(8) bf16 t4[4];
#pragma unroll
                for (int rg = 0; rg < 4; rg++) t4[rg] = __float2bfloat16(acc[mt][nt][rg]);
                *(ull*)(Vt_g + (((size_t)bb * 16 + hh) * 64 + dl) * S + sb) = *(const ull*)t4;
            }
    }
}

// ---------- Flash attention, S^T + transposed-O, single-tile dbuf K-loop
// (round-8 structure; KSCALE pre-folded into Q).
__global__ __launch_bounds__(256) void attn_mfma(const bf16* __restrict__ Q,
                                                 const bf16* __restrict__ K,
                                                 const bf16* __restrict__ Vg,
                                                 bf16* __restrict__ Ctx) {
    __shared__ __align__(16) bf16 Ks[2][BK * DH];   // 8 KB x2, XOR-8 swizzled rows=key
    __shared__ __align__(16) bf16 Vt[2][BK * DH];   // 8 KB x2, rows=dim cols=key
    __shared__ __align__(16) bf16 Qs[BQ * DH];      // 16 KB staging; overlaid by Ps
    bf16* Ps = Qs;   // [128][64], granule(4-elem)-XOR swizzled; rows wave-private

    const int tid = threadIdx.x, wave = tid >> 6, lane = tid & 63;
    const int r16 = lane & 15, quad = lane >> 4;
    const int bh = blockIdx.x, jy = blockIdx.y;
    const int qt = (jy < 8) ? jy : 23 - jy;
    const int b = bh >> 4, h = bh & 15;
    const size_t base  = (size_t)b * S * D + (size_t)h * DH;
    const size_t vbase = (size_t)bh * DH * S;
    const int q0 = qt * BQ;
    const int qwave = q0 + wave * 32;
    const int nkt = 2 * qt + 2;

    // ---- prologue: async-stage Q tile and K/V tile 0 (buf 0)
#pragma unroll
    for (int j = 0; j < 4; j++) {
        const int s = wave * 256 + j * 64 + lane;
        const int r = s >> 3, c = (s ^ r) & 7;
        gload_lds16(Q + base + (size_t)(q0 + r) * D + c * 8, &Qs[(wave * 256 + j * 64) * 8]);
    }
#pragma unroll
    for (int j = 0; j < 2; j++) {
        const int s = wave * 128 + j * 64 + lane;
        const int r = s >> 3, c = (s ^ r) & 7;
        gload_lds16(K  + base  + (size_t)r * D + c * 8, &Ks[0][(wave * 128 + j * 64) * 8]);
        gload_lds16(Vg + vbase + (size_t)r * S + c * 8, &Vt[0][(wave * 128 + j * 64) * 8]);
    }
    __syncthreads();

    // hoist Q B-frags (registers from here on; Qs LDS free to reuse as Ps)
    frag_ab qf[2][2];
#pragma unroll
    for (int nq = 0; nq < 2; nq++)
#pragma unroll
        for (int ks = 0; ks < 2; ks++) {
            const int row = wave * 32 + nq * 16 + r16;
            qf[nq][ks] = *(const frag_ab*)&Qs[row * 64 + (((ks * 4 + quad) ^ (row & 7)) * 8)];
        }

    float mrun[2] = {-1e30f, -1e30f}, lrun[2] = {0.f, 0.f};
    frag_cd Oacc[2][4];   // O^T tile: row=d(quad*4+rg), col=q(r16)
#pragma unroll
    for (int mq = 0; mq < 2; mq++)
#pragma unroll
        for (int nd = 0; nd < 4; nd++) Oacc[mq][nd] = frag_cd{0.f, 0.f, 0.f, 0.f};

    for (int kt = 0; kt < nkt; kt++) {
        const int k0  = kt * BK;
        const int cur = kt & 1;

        // ---- prefetch next K/V tile into alternate buffer (hidden under compute)
        if (kt + 1 < nkt) {
            const int kn = k0 + BK;
#pragma unroll
            for (int j = 0; j < 2; j++) {
                const int s = wave * 128 + j * 64 + lane;
                const int r = s >> 3, c = (s ^ r) & 7;
                gload_lds16(K  + base  + (size_t)(kn + r) * D + c * 8,
                            &Ks[cur ^ 1][(wave * 128 + j * 64) * 8]);
                gload_lds16(Vg + vbase + (size_t)r * S + kn + c * 8,
                            &Vt[cur ^ 1][(wave * 128 + j * 64) * 8]);
            }
        }

        if (k0 <= qwave + 31) {   // wave has unmasked keys in this tile
            frag_ab ka[4][2];
#pragma unroll
            for (int mk = 0; mk < 4; mk++) {
                const int row = mk * 16 + r16;
#pragma unroll
                for (int ks = 0; ks < 2; ks++)
                    ka[mk][ks] = *(const frag_ab*)&Ks[cur][row * 64 + (((ks * 4 + quad) ^ (row & 7)) * 8)];
            }
            const bool domask = (k0 + BK - 1 > qwave);

#pragma unroll
            for (int nq = 0; nq < 2; nq++) {
                frag_cd Sc[4];
#pragma unroll
                for (int mk = 0; mk < 4; mk++) {
                    Sc[mk] = frag_cd{0.f, 0.f, 0.f, 0.f};
#pragma unroll
                    for (int ks = 0; ks < 2; ks++)
                        Sc[mk] = __builtin_amdgcn_mfma_f32_16x16x32_bf16(
                            ka[mk][ks], qf[nq][ks], Sc[mk], 0, 0, 0);
                }
                // S^T C-layout: col(r16)=q, row(quad*4+rg in mk-tile)=key.
                // Scores arrive in log2-domain (KSCALE pre-folded into Q).
                const int qg = q0 + wave * 32 + nq * 16 + r16;
                float mx = -1e30f;
#pragma unroll
                for (int mk = 0; mk < 4; mk++)
#pragma unroll
                    for (int rg = 0; rg < 4; rg++) {
                        float sv = Sc[mk][rg];
                        if (domask) {
                            const int keyg = k0 + mk * 16 + quad * 4 + rg;
                            sv = (keyg <= qg) ? sv : -1e30f;
                        }
                        Sc[mk][rg] = sv;
                        mx = fmaxf(mx, sv);
                    }
                mx = fmaxf(mx, __shfl_xor(mx, 16, 64));
                mx = fmaxf(mx, __shfl_xor(mx, 32, 64));
                const float mnew  = fmaxf(mrun[nq], mx);
                const float alpha = __builtin_amdgcn_exp2f(mrun[nq] - mnew);
                mrun[nq] = mnew;
                float rs = 0.f;
#pragma unroll
                for (int mk = 0; mk < 4; mk++)
#pragma unroll
                    for (int rg = 0; rg < 4; rg++) {
                        const float pv = __builtin_amdgcn_exp2f(Sc[mk][rg] - mnew);
                        Sc[mk][rg] = pv;
                        rs += pv;
                    }
                rs += __shfl_xor(rs, 16, 64);
                rs += __shfl_xor(rs, 32, 64);
                lrun[nq] = lrun[nq] * alpha + rs;

                // packed P write: 4 consecutive keys/lane, granule-XOR swizzle (b64 floor)
                const int qrow = wave * 32 + nq * 16 + r16;
#pragma unroll
                for (int mk = 0; mk < 4; mk++) {
                    __align__(8) bf16 t4[4];
#pragma unroll
                    for (int rg = 0; rg < 4; rg++) t4[rg] = __float2bfloat16(Sc[mk][rg]);
                    const int g = (mk * 4 + quad) ^ r16;
                    *(ull*)&Ps[qrow * 64 + g * 4] = *(const ull*)t4;
                }
                // rescale O^T: col=q=r16 matches alpha's index — direct multiply
#pragma unroll
                for (int nd = 0; nd < 4; nd++)
#pragma unroll
                    for (int rg = 0; rg < 4; rg++) Oacc[nq][nd][rg] *= alpha;
            }
            // no barrier: Ps rows wave-private; per-wave LDS ops are in-order

            // PV (transposed): O^T[d][q] += Vt(d rows) x P(q rows)
            frag_ab pa[2][2], vb[4][2];
#pragma unroll
            for (int mq = 0; mq < 2; mq++) {
                const int row = wave * 32 + mq * 16 + r16;
#pragma unroll
                for (int ks = 0; ks < 2; ks++) {
                    const int gb = ks * 8 + quad * 2;
                    union { ull u[2]; frag_ab f; } t;
                    t.u[0] = *(const ull*)&Ps[row * 64 + ((gb    ) ^ r16) * 4];
                    t.u[1] = *(const ull*)&Ps[row * 64 + ((gb + 1) ^ r16) * 4];
                    pa[mq][ks] = t.f;
                }
            }
#pragma unroll
            for (int nd = 0; nd < 4; nd++) {
                const int row = nd * 16 + r16;
#pragma unroll
                for (int ks = 0; ks < 2; ks++)
                    vb[nd][ks] = *(const frag_ab*)&Vt[cur][row * 64 + (((ks * 4 + quad) ^ (row & 7)) * 8)];
            }
#pragma unroll
            for (int mq = 0; mq < 2; mq++)
#pragma unroll
                for (int nd = 0; nd < 4; nd++)
#pragma unroll
                    for (int ks = 0; ks < 2; ks++)
                        Oacc[mq][nd] = __builtin_amdgcn_mfma_f32_16x16x32_bf16(
                            vb[nd][ks], pa[mq][ks], Oacc[mq][nd], 0, 0, 0);
        }

        __syncthreads();   // joins: prefetch complete + all waves done with cur bufs
    }

    // epilogue: Ctx[q][d] = O^T[d][q] / l — lane holds 4 consecutive d -> packed b64
#pragma unroll
    for (int mq = 0; mq < 2; mq++) {
        const float invl = 1.f / lrun[mq];
        const int qg = q0 + wave * 32 + mq * 16 + r16;
#pragma unroll
        for (int nd = 0; nd < 4; nd++) {
            __align__(8) bf16 t4[4];
#pragma unroll
            for (int rg = 0; rg < 4; rg++)
                t4[rg] = __float2bfloat16(Oacc[mq][nd][rg] * invl);
            *(ull*)(Ctx + base + (size_t)qg * D + nd * 16 + quad * 4) = *(const ull*)t4;
        }
    }
}

// ---------- output projection, 64x128 tiles, single-barrier dbuf K-loop
__global__ __launch_bounds__(256) void gemm_out64(const bf16* __restrict__ A, const bf16* __restrict__ Bt,
                                                  const float* __restrict__ bias, float* __restrict__ Out) {
    __shared__ __align__(16) bf16 As[2][64 * BK];
    __shared__ __align__(16) bf16 Bs[2][128 * BK];
    const int tid = threadIdx.x, wave = tid >> 6, lane = tid & 63;
    const int r16 = lane & 15, quad = lane >> 4;
    const int row0 = blockIdx.y * 64;
    const int col0 = blockIdx.x * 128;
    const int wm = (wave & 1) * 32, wn = (wave >> 1) * 64;

    frag_cd acc[2][4];
#pragma unroll
    for (int mt = 0; mt < 2; mt++)
#pragma unroll
        for (int nt = 0; nt < 4; nt++) acc[mt][nt] = frag_cd{0.f, 0.f, 0.f, 0.f};

#pragma unroll
    for (int j = 0; j < 2; j++) {
        const int s = wave * 128 + j * 64 + lane;
        const int r = s >> 3, c = (s ^ r) & 7;
        gload_lds16(A + (size_t)(row0 + r) * D + c * 8, &As[0][(wave * 128 + j * 64) * 8]);
    }
#pragma unroll
    for (int j = 0; j < 4; j++) {
        const int s = wave * 256 + j * 64 + lane;
        const int r = s >> 3, c = (s ^ r) & 7;
        gload_lds16(Bt + (size_t)(col0 + r) * D + c * 8, &Bs[0][(wave * 256 + j * 64) * 8]);
    }
    __syncthreads();

    for (int kt = 0; kt < D / BK; kt++) {
        const int cur = kt & 1;
        if (kt + 1 < D / BK) {
            const int kn = (kt + 1) * BK;
#pragma unroll
            for (int j = 0; j < 2; j++) {
                const int s = wave * 128 + j * 64 + lane;
                const int r = s >> 3, c = (s ^ r) & 7;
                gload_lds16(A + (size_t)(row0 + r) * D + kn + c * 8,
                            &As[cur ^ 1][(wave * 128 + j * 64) * 8]);
            }
#pragma unroll
            for (int j = 0; j < 4; j++) {
                const int s = wave * 256 + j * 64 + lane;
                const int r = s >> 3, c = (s ^ r) & 7;
                gload_lds16(Bt + (size_t)(col0 + r) * D + kn + c * 8,
                            &Bs[cur ^ 1][(wave * 256 + j * 64) * 8]);
            }
        }

        frag_ab af[2][2], bf[4][2];
#pragma unroll
        for (int mt = 0; mt < 2; mt++) {
            const int row = wm + mt * 16 + r16;
#pragma unroll
            for (int ks = 0; ks < 2; ks++)
                af[mt][ks] = *(const frag_ab*)&As[cur][row * 64 + (((ks * 4 + quad) ^ (row & 7)) * 8)];
        }
#pragma unroll
        for (int nt = 0; nt < 4; nt++) {
            const int row = wn + nt * 16 + r16;
#pragma unroll
            for (int ks = 0; ks < 2; ks++)
                bf[nt][ks] = *(const frag_ab*)&Bs[cur][row * 64 + (((ks * 4 + quad) ^ (row & 7)) * 8)];
        }
#pragma unroll
        for (int mt = 0; mt < 2; mt++)
#pragma unroll
            for (int nt = 0; nt < 4; nt++)
#pragma unroll
                for (int ks = 0; ks < 2; ks++)
                    acc[mt][nt] = __builtin_amdgcn_mfma_f32_16x16x32_bf16(
                        af[mt][ks], bf[nt][ks], acc[mt][nt], 0, 0, 0);

        __syncthreads();
    }

#pragma unroll
    for (int mt = 0; mt < 2; mt++)
#pragma unroll
        for (int nt = 0; nt < 4; nt++) {
            const int col = col0 + wn + nt * 16 + r16;
            const float bv = bias[col];
#pragma unroll
            for (int rg = 0; rg < 4; rg++) {
                const int row = row0 + wm + mt * 16 + quad * 4 + rg;
                Out[(size_t)row * D + col] = acc[mt][nt][rg] + bv;
            }
        }
}

extern "C" void kernel_launch(void* const* d_in, const int* in_sizes, int n_in,
                              void* d_out, int out_size, void* d_ws, size_t ws_size,
                              hipStream_t stream) {
    const float* x  = (const float*)d_in[0];
    const float* Wq = (const float*)d_in[1];
    const float* Wk = (const float*)d_in[2];
    const float* Wv = (const float*)d_in[3];
    const float* Wo = (const float*)d_in[4];
    const float* bo = (const float*)d_in[5];
    float* out = (float*)d_out;

    bf16* xb    = (bf16*)d_ws;                 // [4096][1024]
    bf16* WqkvT = xb    + (size_t)M * D;       // [3072][1024] (WqT|WkT|WvT)
    bf16* WoT   = WqkvT + (size_t)3 * D * D;   // [1024][1024]
    bf16* Qb    = WoT   + (size_t)D * D;       // [B,S,D] (pre-scaled by KSCALE)
    bf16* Kb    = Qb    + (size_t)M * D;       // [B,S,D]
    bf16* Vt_g  = Kb    + (size_t)M * D;       // [32][64][2048]
    bf16* Ctxb  = Vt_g  + (size_t)M * D;       // [B,S,D]

    cvt_x<<<(M * D) / 1024, 256, 0, stream>>>(x, xb);
    cvt_wT<<<dim3(32, 32, 4), 256, 0, stream>>>(Wq, Wk, Wv, Wo,
                                                WqkvT, WqkvT + (size_t)D * D,
                                                WqkvT + (size_t)2 * D * D, WoT);
    gemm_qkv_all<<<dim3(24, 64), 256, 0, stream>>>(xb, WqkvT, Qb, Kb, Vt_g);
    attn_mfma<<<dim3(B * NH, S / BQ), 256, 0, stream>>>(Qb, Kb, Vt_g, Ctxb);
    gemm_out64<<<dim3(8, 64), 256, 0, stream>>>(Ctxb, WoT, bo, out);
}

// Round 11
// 181.016 us; speedup vs baseline: 1.1008x; 1.1008x over previous
//
#include <hip/hip_runtime.h>
#include <hip/hip_bf16.h>

#define B 2
#define S 2048
#define D 1024
#define NH 16
#define DH 64
#define M (B*S)
#define BQ 64
#define BK 64
#define KSCALE 0.18033688011112042f   // (1/sqrt(64)) * log2(e) — folded into Qb

typedef __hip_bfloat16 bf16;
typedef __attribute__((ext_vector_type(8))) short frag_ab;   // 8 bf16
typedef __attribute__((ext_vector_type(4))) float frag_cd;   // 4 f32
typedef unsigned long long ull;

// async global->LDS, 16B/lane; LDS dest = wave-uniform base + lane*16
__device__ __forceinline__ void gload_lds16(const bf16* g, bf16* l) {
    __builtin_amdgcn_global_load_lds((const __attribute__((address_space(1))) unsigned int*)g,
                                     (__attribute__((address_space(3))) unsigned int*)l,
                                     16, 0, 0);
}

// ---------- convert x fp32 -> bf16
__global__ __launch_bounds__(256) void cvt_x(const float* __restrict__ x, bf16* __restrict__ xb) {
    const int i = (blockIdx.x * 256 + threadIdx.x) * 4;
    const float4 v = *(const float4*)(x + i);
    __align__(8) bf16 t[4] = {__float2bfloat16(v.x), __float2bfloat16(v.y),
                              __float2bfloat16(v.z), __float2bfloat16(v.w)};
    *(ull*)(xb + i) = *(const ull*)t;
}

// ---------- convert + transpose weights: T[n][k] = W[k][n]
__global__ __launch_bounds__(256) void cvt_wT(const float* __restrict__ W0, const float* __restrict__ W1,
                                              const float* __restrict__ W2, const float* __restrict__ W3,
                                              bf16* __restrict__ T0, bf16* __restrict__ T1,
                                              bf16* __restrict__ T2, bf16* __restrict__ T3) {
    const float* src; bf16* dst;
    switch (blockIdx.z) {
        case 0: src = W0; dst = T0; break;
        case 1: src = W1; dst = T1; break;
        case 2: src = W2; dst = T2; break;
        default: src = W3; dst = T3; break;
    }
    __shared__ float t[32][33];
    const int tx = threadIdx.x & 31, ty = threadIdx.x >> 5;
    const int c0 = blockIdx.x * 32, r0 = blockIdx.y * 32;
#pragma unroll
    for (int i = 0; i < 4; i++)
        t[ty + 8 * i][tx] = src[(size_t)(r0 + ty + 8 * i) * D + c0 + tx];
    __syncthreads();
#pragma unroll
    for (int i = 0; i < 4; i++)
        dst[(size_t)(c0 + ty + 8 * i) * D + r0 + tx] = __float2bfloat16(t[tx][ty + 8 * i]);
}

// ---------- fused QKV GEMM (round-9 structure): 128x128 tiles, 2-barrier K-loop,
// grid (24,32). Q third PRE-SCALED by KSCALE; K row-major; V third TRANSPOSED: Vt[bh][d][s].
__global__ __launch_bounds__(256) void gemm_qkv_all(const bf16* __restrict__ A, const bf16* __restrict__ Bt,
                                                    bf16* __restrict__ Qb, bf16* __restrict__ Kb,
                                                    bf16* __restrict__ Vt_g) {
    __shared__ __align__(16) bf16 As[128 * BK];
    __shared__ __align__(16) bf16 Bs[128 * BK];
    const int tid = threadIdx.x, wave = tid >> 6, lane = tid & 63;
    const int r16 = lane & 15, quad = lane >> 4;
    const int row0 = blockIdx.y * 128;
    const int col0 = blockIdx.x * 128;
    const int wm = (wave & 1) * 64, wn = (wave >> 1) * 64;

    frag_cd acc[4][4];
#pragma unroll
    for (int mt = 0; mt < 4; mt++)
#pragma unroll
        for (int nt = 0; nt < 4; nt++) acc[mt][nt] = frag_cd{0.f, 0.f, 0.f, 0.f};

    for (int k0 = 0; k0 < D; k0 += BK) {
        __syncthreads();
#pragma unroll
        for (int j = 0; j < 4; j++) {
            const int s = wave * 256 + j * 64 + lane;
            const int r = s >> 3;
            const int c = (s ^ r) & 7;
            gload_lds16(A  + (size_t)(row0 + r) * D + k0 + c * 8, &As[(wave * 256 + j * 64) * 8]);
            gload_lds16(Bt + (size_t)(col0 + r) * D + k0 + c * 8, &Bs[(wave * 256 + j * 64) * 8]);
        }
        __syncthreads();

        frag_ab af[4][2], bf[4][2];
#pragma unroll
        for (int mt = 0; mt < 4; mt++) {
            const int row = wm + mt * 16 + r16;
#pragma unroll
            for (int ks = 0; ks < 2; ks++)
                af[mt][ks] = *(const frag_ab*)&As[row * 64 + (((ks * 4 + quad) ^ (row & 7)) * 8)];
        }
#pragma unroll
        for (int nt = 0; nt < 4; nt++) {
            const int row = wn + nt * 16 + r16;
#pragma unroll
            for (int ks = 0; ks < 2; ks++)
                bf[nt][ks] = *(const frag_ab*)&Bs[row * 64 + (((ks * 4 + quad) ^ (row & 7)) * 8)];
        }
#pragma unroll
        for (int mt = 0; mt < 4; mt++)
#pragma unroll
            for (int nt = 0; nt < 4; nt++)
#pragma unroll
                for (int ks = 0; ks < 2; ks++)
                    acc[mt][nt] = __builtin_amdgcn_mfma_f32_16x16x32_bf16(
                        af[mt][ks], bf[nt][ks], acc[mt][nt], 0, 0, 0);
    }

    const int third = col0 >> 10;
    if (third < 2) {
        bf16* Out = (third == 0) ? Qb : Kb;
        const float sc = (third == 0) ? KSCALE : 1.f;
#pragma unroll
        for (int mt = 0; mt < 4; mt++)
#pragma unroll
            for (int nt = 0; nt < 4; nt++) {
                const int cl = (col0 + wn + nt * 16 + r16) & 1023;
#pragma unroll
                for (int rg = 0; rg < 4; rg++) {
                    const int row = row0 + wm + mt * 16 + quad * 4 + rg;
                    Out[(size_t)row * D + cl] = __float2bfloat16(acc[mt][nt][rg] * sc);
                }
            }
    } else {
        const int bb = row0 >> 11;
        const int sb0 = (row0 & 2047) + wm;
#pragma unroll
        for (int mt = 0; mt < 4; mt++)
#pragma unroll
            for (int nt = 0; nt < 4; nt++) {
                const int c  = (col0 + wn + nt * 16 + r16) - 2048;
                const int hh = c >> 6, dl = c & 63;
                const int sb = sb0 + mt * 16 + quad * 4;
                __align__(8) bf16 t4[4];
#pragma unroll
                for (int rg = 0; rg < 4; rg++) t4[rg] = __float2bfloat16(acc[mt][nt][rg]);
                *(ull*)(Vt_g + (((size_t)bb * 16 + hh) * 64 + dl) * S + sb) = *(const ull*)t4;
            }
    }
}

// ---------- Flash attention, S^T + transposed-O, dbuf K-loop, BQ=64:
// grid (32 bh, 32 q-tiles) = 1024 blocks = 4/CU; wave owns one 16-row q-band.
__global__ __launch_bounds__(256) void attn_mfma(const bf16* __restrict__ Q,
                                                 const bf16* __restrict__ K,
                                                 const bf16* __restrict__ Vg,
                                                 bf16* __restrict__ Ctx) {
    __shared__ __align__(16) bf16 Ks[2][BK * DH];   // 8 KB x2, XOR-8 swizzled rows=key
    __shared__ __align__(16) bf16 Vt[2][BK * DH];   // 8 KB x2, rows=dim cols=key
    __shared__ __align__(16) bf16 Qs[BQ * DH];      // 8 KB staging; overlaid by Ps
    bf16* Ps = Qs;   // [64][64], granule(4-elem)-XOR swizzled; rows wave-private

    const int tid = threadIdx.x, wave = tid >> 6, lane = tid & 63;
    const int r16 = lane & 15, quad = lane >> 4;
    const int bh = blockIdx.x, jy = blockIdx.y;
    const int qt = (jy < 16) ? jy : 47 - jy;   // pair-balanced
    const int b = bh >> 4, h = bh & 15;
    const size_t base  = (size_t)b * S * D + (size_t)h * DH;
    const size_t vbase = (size_t)bh * DH * S;
    const int q0 = qt * BQ;
    const int qwave = q0 + wave * 16;
    const int nkt = qt + 1;

    // ---- prologue: async-stage Q tile (64x64) and K/V tile 0 (buf 0)
#pragma unroll
    for (int j = 0; j < 2; j++) {
        const int s = wave * 128 + j * 64 + lane;
        const int r = s >> 3, c = (s ^ r) & 7;
        gload_lds16(Q + base + (size_t)(q0 + r) * D + c * 8, &Qs[(wave * 128 + j * 64) * 8]);
    }
#pragma unroll
    for (int j = 0; j < 2; j++) {
        const int s = wave * 128 + j * 64 + lane;
        const int r = s >> 3, c = (s ^ r) & 7;
        gload_lds16(K  + base  + (size_t)r * D + c * 8, &Ks[0][(wave * 128 + j * 64) * 8]);
        gload_lds16(Vg + vbase + (size_t)r * S + c * 8, &Vt[0][(wave * 128 + j * 64) * 8]);
    }
    __syncthreads();

    // hoist Q B-frag (loop-invariant); Qs LDS then reusable as Ps
    frag_ab qf[2];
    {
        const int row = wave * 16 + r16;
#pragma unroll
        for (int ks = 0; ks < 2; ks++)
            qf[ks] = *(const frag_ab*)&Qs[row * 64 + (((ks * 4 + quad) ^ (row & 7)) * 8)];
    }

    float mrun = -1e30f, lrun = 0.f;
    frag_cd Oacc[4];   // O^T tiles: row=d(quad*4+rg), col=q(r16)
#pragma unroll
    for (int nd = 0; nd < 4; nd++) Oacc[nd] = frag_cd{0.f, 0.f, 0.f, 0.f};

    for (int kt = 0; kt < nkt; kt++) {
        const int k0  = kt * BK;
        const int cur = kt & 1;

        // ---- prefetch next K/V tile into alternate buffer (hidden under compute)
        if (kt + 1 < nkt) {
            const int kn = k0 + BK;
#pragma unroll
            for (int j = 0; j < 2; j++) {
                const int s = wave * 128 + j * 64 + lane;
                const int r = s >> 3, c = (s ^ r) & 7;
                gload_lds16(K  + base  + (size_t)(kn + r) * D + c * 8,
                            &Ks[cur ^ 1][(wave * 128 + j * 64) * 8]);
                gload_lds16(Vg + vbase + (size_t)r * S + kn + c * 8,
                            &Vt[cur ^ 1][(wave * 128 + j * 64) * 8]);
            }
        }

        if (k0 <= qwave + 15) {   // wave has unmasked keys in this tile
            frag_ab ka[4][2];
#pragma unroll
            for (int mk = 0; mk < 4; mk++) {
                const int row = mk * 16 + r16;
#pragma unroll
                for (int ks = 0; ks < 2; ks++)
                    ka[mk][ks] = *(const frag_ab*)&Ks[cur][row * 64 + (((ks * 4 + quad) ^ (row & 7)) * 8)];
            }
            const bool domask = (k0 + BK - 1 > qwave);

            frag_cd Sc[4];
#pragma unroll
            for (int mk = 0; mk < 4; mk++) {
                Sc[mk] = frag_cd{0.f, 0.f, 0.f, 0.f};
#pragma unroll
                for (int ks = 0; ks < 2; ks++)
                    Sc[mk] = __builtin_amdgcn_mfma_f32_16x16x32_bf16(
                        ka[mk][ks], qf[ks], Sc[mk], 0, 0, 0);
            }
            // S^T C-layout: col(r16)=q, row(quad*4+rg in mk-tile)=key.
            // Scores arrive in log2-domain (KSCALE pre-folded into Q).
            const int qg = qwave + r16;
            float mx = -1e30f;
#pragma unroll
            for (int mk = 0; mk < 4; mk++)
#pragma unroll
                for (int rg = 0; rg < 4; rg++) {
                    float sv = Sc[mk][rg];
                    if (domask) {
                        const int keyg = k0 + mk * 16 + quad * 4 + rg;
                        sv = (keyg <= qg) ? sv : -1e30f;
                    }
                    Sc[mk][rg] = sv;
                    mx = fmaxf(mx, sv);
                }
            mx = fmaxf(mx, __shfl_xor(mx, 16, 64));
            mx = fmaxf(mx, __shfl_xor(mx, 32, 64));
            const float mnew  = fmaxf(mrun, mx);
            const float alpha = __builtin_amdgcn_exp2f(mrun - mnew);
            mrun = mnew;
            float rs = 0.f;
#pragma unroll
            for (int mk = 0; mk < 4; mk++)
#pragma unroll
                for (int rg = 0; rg < 4; rg++) {
                    const float pv = __builtin_amdgcn_exp2f(Sc[mk][rg] - mnew);
                    Sc[mk][rg] = pv;
                    rs += pv;
                }
            rs += __shfl_xor(rs, 16, 64);
            rs += __shfl_xor(rs, 32, 64);
            lrun = lrun * alpha + rs;

            // packed P write: 4 consecutive keys/lane, granule-XOR swizzle (b64 floor)
            const int qrow = wave * 16 + r16;
#pragma unroll
            for (int mk = 0; mk < 4; mk++) {
                __align__(8) bf16 t4[4];
#pragma unroll
                for (int rg = 0; rg < 4; rg++) t4[rg] = __float2bfloat16(Sc[mk][rg]);
                const int g = (mk * 4 + quad) ^ r16;
                *(ull*)&Ps[qrow * 64 + g * 4] = *(const ull*)t4;
            }
            // rescale O^T: col=q=r16 matches alpha's index — direct multiply
#pragma unroll
            for (int nd = 0; nd < 4; nd++)
#pragma unroll
                for (int rg = 0; rg < 4; rg++) Oacc[nd][rg] *= alpha;

            // no barrier: Ps rows wave-private; per-wave LDS ops are in-order

            // PV (transposed): O^T[d][q] += Vt(d rows) x P(q rows)
            frag_ab pa[2], vb[4][2];
#pragma unroll
            for (int ks = 0; ks < 2; ks++) {
                const int gb = ks * 8 + quad * 2;
                union { ull u[2]; frag_ab f; } t;
                t.u[0] = *(const ull*)&Ps[qrow * 64 + ((gb    ) ^ r16) * 4];
                t.u[1] = *(const ull*)&Ps[qrow * 64 + ((gb + 1) ^ r16) * 4];
                pa[ks] = t.f;
            }
#pragma unroll
            for (int nd = 0; nd < 4; nd++) {
                const int row = nd * 16 + r16;
#pragma unroll
                for (int ks = 0; ks < 2; ks++)
                    vb[nd][ks] = *(const frag_ab*)&Vt[cur][row * 64 + (((ks * 4 + quad) ^ (row & 7)) * 8)];
            }
#pragma unroll
            for (int nd = 0; nd < 4; nd++)
#pragma unroll
                for (int ks = 0; ks < 2; ks++)
                    Oacc[nd] = __builtin_amdgcn_mfma_f32_16x16x32_bf16(
                        vb[nd][ks], pa[ks], Oacc[nd], 0, 0, 0);
        }

        __syncthreads();   // joins: prefetch complete + all waves done with cur bufs
    }

    // epilogue: Ctx[q][d] = O^T[d][q] / l — lane holds 4 consecutive d -> packed b64
    {
        const float invl = 1.f / lrun;
        const int qg = qwave + r16;
#pragma unroll
        for (int nd = 0; nd < 4; nd++) {
            __align__(8) bf16 t4[4];
#pragma unroll
            for (int rg = 0; rg < 4; rg++)
                t4[rg] = __float2bfloat16(Oacc[nd][rg] * invl);
            *(ull*)(Ctx + base + (size_t)qg * D + nd * 16 + quad * 4) = *(const ull*)t4;
        }
    }
}

// ---------- output projection (round-9 structure), 64x128 tiles, 2-barrier K-loop
__global__ __launch_bounds__(256) void gemm_out64(const bf16* __restrict__ A, const bf16* __restrict__ Bt,
                                                  const float* __restrict__ bias, float* __restrict__ Out) {
    __shared__ __align__(16) bf16 As[64 * BK];
    __shared__ __align__(16) bf16 Bs[128 * BK];
    const int tid = threadIdx.x, wave = tid >> 6, lane = tid & 63;
    const int r16 = lane & 15, quad = lane >> 4;
    const int row0 = blockIdx.y * 64;
    const int col0 = blockIdx.x * 128;
    const int wm = (wave & 1) * 32, wn = (wave >> 1) * 64;

    frag_cd acc[2][4];
#pragma unroll
    for (int mt = 0; mt < 2; mt++)
#pragma unroll
        for (int nt = 0; nt < 4; nt++) acc[mt][nt] = frag_cd{0.f, 0.f, 0.f, 0.f};

    for (int k0 = 0; k0 < D; k0 += BK) {
        __syncthreads();
#pragma unroll
        for (int j = 0; j < 2; j++) {
            const int s = wave * 128 + j * 64 + lane;
            const int r = s >> 3, c = (s ^ r) & 7;
            gload_lds16(A + (size_t)(row0 + r) * D + k0 + c * 8, &As[(wave * 128 + j * 64) * 8]);
        }
#pragma unroll
        for (int j = 0; j < 4; j++) {
            const int s = wave * 256 + j * 64 + lane;
            const int r = s >> 3, c = (s ^ r) & 7;
            gload_lds16(Bt + (size_t)(col0 + r) * D + k0 + c * 8, &Bs[(wave * 256 + j * 64) * 8]);
        }
        __syncthreads();

        frag_ab af[2][2], bf[4][2];
#pragma unroll
        for (int mt = 0; mt < 2; mt++) {
            const int row = wm + mt * 16 + r16;
#pragma unroll
            for (int ks = 0; ks < 2; ks++)
                af[mt][ks] = *(const frag_ab*)&As[row * 64 + (((ks * 4 + quad) ^ (row & 7)) * 8)];
        }
#pragma unroll
        for (int nt = 0; nt < 4; nt++) {
            const int row = wn + nt * 16 + r16;
#pragma unroll
            for (int ks = 0; ks < 2; ks++)
                bf[nt][ks] = *(const frag_ab*)&Bs[row * 64 + (((ks * 4 + quad) ^ (row & 7)) * 8)];
        }
#pragma unroll
        for (int mt = 0; mt < 2; mt++)
#pragma unroll
            for (int nt = 0; nt < 4; nt++)
#pragma unroll
                for (int ks = 0; ks < 2; ks++)
                    acc[mt][nt] = __builtin_amdgcn_mfma_f32_16x16x32_bf16(
                        af[mt][ks], bf[nt][ks], acc[mt][nt], 0, 0, 0);
    }

#pragma unroll
    for (int mt = 0; mt < 2; mt++)
#pragma unroll
        for (int nt = 0; nt < 4; nt++) {
            const int col = col0 + wn + nt * 16 + r16;
            const float bv = bias[col];
#pragma unroll
            for (int rg = 0; rg < 4; rg++) {
                const int row = row0 + wm + mt * 16 + quad * 4 + rg;
                Out[(size_t)row * D + col] = acc[mt][nt][rg] + bv;
            }
        }
}

extern "C" void kernel_launch(void* const* d_in, const int* in_sizes, int n_in,
                              void* d_out, int out_size, void* d_ws, size_t ws_size,
                              hipStream_t stream) {
    const float* x  = (const float*)d_in[0];
    const float* Wq = (const float*)d_in[1];
    const float* Wk = (const float*)d_in[2];
    const float* Wv = (const float*)d_in[3];
    const float* Wo = (const float*)d_in[4];
    const float* bo = (const float*)d_in[5];
    float* out = (float*)d_out;

    bf16* xb    = (bf16*)d_ws;                 // [4096][1024]
    bf16* WqkvT = xb    + (size_t)M * D;       // [3072][1024] (WqT|WkT|WvT)
    bf16* WoT   = WqkvT + (size_t)3 * D * D;   // [1024][1024]
    bf16* Qb    = WoT   + (size_t)D * D;       // [B,S,D] (pre-scaled by KSCALE)
    bf16* Kb    = Qb    + (size_t)M * D;       // [B,S,D]
    bf16* Vt_g  = Kb    + (size_t)M * D;       // [32][64][2048]
    bf16* Ctxb  = Vt_g  + (size_t)M * D;       // [B,S,D]

    cvt_x<<<(M * D) / 1024, 256, 0, stream>>>(x, xb);
    cvt_wT<<<dim3(32, 32, 4), 256, 0, stream>>>(Wq, Wk, Wv, Wo,
                                                WqkvT, WqkvT + (size_t)D * D,
                                                WqkvT + (size_t)2 * D * D, WoT);
    gemm_qkv_all<<<dim3(24, 32), 256, 0, stream>>>(xb, WqkvT, Qb, Kb, Vt_g);
    attn_mfma<<<dim3(B * NH, S / BQ), 256, 0, stream>>>(Qb, Kb, Vt_g, Ctxb);
    gemm_out64<<<dim3(8, 64), 256, 0, stream>>>(Ctxb, WoT, bo, out);
}

// Round 12
// 180.681 us; speedup vs baseline: 1.1028x; 1.0019x over previous
//
#include <hip/hip_runtime.h>
#include <hip/hip_bf16.h>

#define B 2
#define S 2048
#define D 1024
#define NH 16
#define DH 64
#define M (B*S)
#define BQ 64
#define BK 64
#define KSCALE 0.18033688011112042f   // (1/sqrt(64)) * log2(e) — folded into Qb

typedef __hip_bfloat16 bf16;
typedef __attribute__((ext_vector_type(8))) short frag_ab;   // 8 bf16
typedef __attribute__((ext_vector_type(4))) float frag_cd;   // 4 f32
typedef unsigned long long ull;

// async global->LDS, 16B/lane; LDS dest = wave-uniform base + lane*16
__device__ __forceinline__ void gload_lds16(const bf16* g, bf16* l) {
    __builtin_amdgcn_global_load_lds((const __attribute__((address_space(1))) unsigned int*)g,
                                     (__attribute__((address_space(3))) unsigned int*)l,
                                     16, 0, 0);
}

// ---------- prep: z=0..3 -> weight convert+transpose T[n][k]=W[k][n]; z=4 -> x fp32->bf16
__global__ __launch_bounds__(256) void prep(const float* __restrict__ x,  bf16* __restrict__ xb,
                                            const float* __restrict__ W0, const float* __restrict__ W1,
                                            const float* __restrict__ W2, const float* __restrict__ W3,
                                            bf16* __restrict__ T0, bf16* __restrict__ T1,
                                            bf16* __restrict__ T2, bf16* __restrict__ T3) {
    if (blockIdx.z == 4) {
        const int l = blockIdx.y * 32 + blockIdx.x;
        int i = (l * 256 + threadIdx.x) * 4;
#pragma unroll
        for (int rep = 0; rep < 4; rep++, i += 1024 * 256 * 4) {
            const float4 v = *(const float4*)(x + i);
            __align__(8) bf16 t4[4] = {__float2bfloat16(v.x), __float2bfloat16(v.y),
                                       __float2bfloat16(v.z), __float2bfloat16(v.w)};
            *(ull*)(xb + i) = *(const ull*)t4;
        }
        return;
    }
    const float* src; bf16* dst;
    switch (blockIdx.z) {
        case 0: src = W0; dst = T0; break;
        case 1: src = W1; dst = T1; break;
        case 2: src = W2; dst = T2; break;
        default: src = W3; dst = T3; break;
    }
    __shared__ float t[32][33];
    const int tx = threadIdx.x & 31, ty = threadIdx.x >> 5;
    const int c0 = blockIdx.x * 32, r0 = blockIdx.y * 32;
#pragma unroll
    for (int i = 0; i < 4; i++)
        t[ty + 8 * i][tx] = src[(size_t)(r0 + ty + 8 * i) * D + c0 + tx];
    __syncthreads();
#pragma unroll
    for (int i = 0; i < 4; i++)
        dst[(size_t)(c0 + ty + 8 * i) * D + r0 + tx] = __float2bfloat16(t[tx][ty + 8 * i]);
}

// ---------- fused QKV GEMM: 128x128 tiles, 2-barrier K-loop, grid (24,32).
// Q third PRE-SCALED by KSCALE; K row-major; V third TRANSPOSED: Vt[bh][d][s].
__global__ __launch_bounds__(256) void gemm_qkv_all(const bf16* __restrict__ A, const bf16* __restrict__ Bt,
                                                    bf16* __restrict__ Qb, bf16* __restrict__ Kb,
                                                    bf16* __restrict__ Vt_g) {
    __shared__ __align__(16) bf16 As[128 * BK];
    __shared__ __align__(16) bf16 Bs[128 * BK];
    const int tid = threadIdx.x, wave = tid >> 6, lane = tid & 63;
    const int r16 = lane & 15, quad = lane >> 4;
    const int row0 = blockIdx.y * 128;
    const int col0 = blockIdx.x * 128;
    const int wm = (wave & 1) * 64, wn = (wave >> 1) * 64;

    frag_cd acc[4][4];
#pragma unroll
    for (int mt = 0; mt < 4; mt++)
#pragma unroll
        for (int nt = 0; nt < 4; nt++) acc[mt][nt] = frag_cd{0.f, 0.f, 0.f, 0.f};

    for (int k0 = 0; k0 < D; k0 += BK) {
        __syncthreads();
#pragma unroll
        for (int j = 0; j < 4; j++) {
            const int s = wave * 256 + j * 64 + lane;
            const int r = s >> 3;
            const int c = (s ^ r) & 7;
            gload_lds16(A  + (size_t)(row0 + r) * D + k0 + c * 8, &As[(wave * 256 + j * 64) * 8]);
            gload_lds16(Bt + (size_t)(col0 + r) * D + k0 + c * 8, &Bs[(wave * 256 + j * 64) * 8]);
        }
        __syncthreads();

        frag_ab af[4][2], bf[4][2];
#pragma unroll
        for (int mt = 0; mt < 4; mt++) {
            const int row = wm + mt * 16 + r16;
#pragma unroll
            for (int ks = 0; ks < 2; ks++)
                af[mt][ks] = *(const frag_ab*)&As[row * 64 + (((ks * 4 + quad) ^ (row & 7)) * 8)];
        }
#pragma unroll
        for (int nt = 0; nt < 4; nt++) {
            const int row = wn + nt * 16 + r16;
#pragma unroll
            for (int ks = 0; ks < 2; ks++)
                bf[nt][ks] = *(const frag_ab*)&Bs[row * 64 + (((ks * 4 + quad) ^ (row & 7)) * 8)];
        }
#pragma unroll
        for (int mt = 0; mt < 4; mt++)
#pragma unroll
            for (int nt = 0; nt < 4; nt++)
#pragma unroll
                for (int ks = 0; ks < 2; ks++)
                    acc[mt][nt] = __builtin_amdgcn_mfma_f32_16x16x32_bf16(
                        af[mt][ks], bf[nt][ks], acc[mt][nt], 0, 0, 0);
    }

    const int third = col0 >> 10;
    if (third < 2) {
        bf16* Out = (third == 0) ? Qb : Kb;
        const float sc = (third == 0) ? KSCALE : 1.f;
#pragma unroll
        for (int mt = 0; mt < 4; mt++)
#pragma unroll
            for (int nt = 0; nt < 4; nt++) {
                const int cl = (col0 + wn + nt * 16 + r16) & 1023;
#pragma unroll
                for (int rg = 0; rg < 4; rg++) {
                    const int row = row0 + wm + mt * 16 + quad * 4 + rg;
                    Out[(size_t)row * D + cl] = __float2bfloat16(acc[mt][nt][rg] * sc);
                }
            }
    } else {
        const int bb = row0 >> 11;
        const int sb0 = (row0 & 2047) + wm;
#pragma unroll
        for (int mt = 0; mt < 4; mt++)
#pragma unroll
            for (int nt = 0; nt < 4; nt++) {
                const int c  = (col0 + wn + nt * 16 + r16) - 2048;
                const int hh = c >> 6, dl = c & 63;
                const int sb = sb0 + mt * 16 + quad * 4;
                __align__(8) bf16 t4[4];
#pragma unroll
                for (int rg = 0; rg < 4; rg++) t4[rg] = __float2bfloat16(acc[mt][nt][rg]);
                *(ull*)(Vt_g + (((size_t)bb * 16 + hh) * 64 + dl) * S + sb) = *(const ull*)t4;
            }
    }
}

// ---------- Flash attention, S^T + transposed-O, dbuf K-loop, BQ=64 (R11 best)
__global__ __launch_bounds__(256) void attn_mfma(const bf16* __restrict__ Q,
                                                 const bf16* __restrict__ K,
                                                 const bf16* __restrict__ Vg,
                                                 bf16* __restrict__ Ctx) {
    __shared__ __align__(16) bf16 Ks[2][BK * DH];   // 8 KB x2, XOR-8 swizzled rows=key
    __shared__ __align__(16) bf16 Vt[2][BK * DH];   // 8 KB x2, rows=dim cols=key
    __shared__ __align__(16) bf16 Qs[BQ * DH];      // 8 KB staging; overlaid by Ps
    bf16* Ps = Qs;   // [64][64], granule(4-elem)-XOR swizzled; rows wave-private

    const int tid = threadIdx.x, wave = tid >> 6, lane = tid & 63;
    const int r16 = lane & 15, quad = lane >> 4;
    const int bh = blockIdx.x, jy = blockIdx.y;
    const int qt = (jy < 16) ? jy : 47 - jy;   // per-CU balanced (sum=66 iters/CU)
    const int b = bh >> 4, h = bh & 15;
    const size_t base  = (size_t)b * S * D + (size_t)h * DH;
    const size_t vbase = (size_t)bh * DH * S;
    const int q0 = qt * BQ;
    const int qwave = q0 + wave * 16;
    const int nkt = qt + 1;

    // ---- prologue: async-stage Q tile (64x64) and K/V tile 0 (buf 0)
#pragma unroll
    for (int j = 0; j < 2; j++) {
        const int s = wave * 128 + j * 64 + lane;
        const int r = s >> 3, c = (s ^ r) & 7;
        gload_lds16(Q + base + (size_t)(q0 + r) * D + c * 8, &Qs[(wave * 128 + j * 64) * 8]);
    }
#pragma unroll
    for (int j = 0; j < 2; j++) {
        const int s = wave * 128 + j * 64 + lane;
        const int r = s >> 3, c = (s ^ r) & 7;
        gload_lds16(K  + base  + (size_t)r * D + c * 8, &Ks[0][(wave * 128 + j * 64) * 8]);
        gload_lds16(Vg + vbase + (size_t)r * S + c * 8, &Vt[0][(wave * 128 + j * 64) * 8]);
    }
    __syncthreads();

    // hoist Q B-frag (loop-invariant); Qs LDS then reusable as Ps
    frag_ab qf[2];
    {
        const int row = wave * 16 + r16;
#pragma unroll
        for (int ks = 0; ks < 2; ks++)
            qf[ks] = *(const frag_ab*)&Qs[row * 64 + (((ks * 4 + quad) ^ (row & 7)) * 8)];
    }

    float mrun = -1e30f, lrun = 0.f;
    frag_cd Oacc[4];   // O^T tiles: row=d(quad*4+rg), col=q(r16)
#pragma unroll
    for (int nd = 0; nd < 4; nd++) Oacc[nd] = frag_cd{0.f, 0.f, 0.f, 0.f};

    for (int kt = 0; kt < nkt; kt++) {
        const int k0  = kt * BK;
        const int cur = kt & 1;

        // ---- prefetch next K/V tile into alternate buffer (hidden under compute)
        if (kt + 1 < nkt) {
            const int kn = k0 + BK;
#pragma unroll
            for (int j = 0; j < 2; j++) {
                const int s = wave * 128 + j * 64 + lane;
                const int r = s >> 3, c = (s ^ r) & 7;
                gload_lds16(K  + base  + (size_t)(kn + r) * D + c * 8,
                            &Ks[cur ^ 1][(wave * 128 + j * 64) * 8]);
                gload_lds16(Vg + vbase + (size_t)r * S + kn + c * 8,
                            &Vt[cur ^ 1][(wave * 128 + j * 64) * 8]);
            }
        }

        {
            frag_ab ka[4][2];
#pragma unroll
            for (int mk = 0; mk < 4; mk++) {
                const int row = mk * 16 + r16;
#pragma unroll
                for (int ks = 0; ks < 2; ks++)
                    ka[mk][ks] = *(const frag_ab*)&Ks[cur][row * 64 + (((ks * 4 + quad) ^ (row & 7)) * 8)];
            }
            const bool domask = (k0 + BK - 1 > qwave);

            frag_cd Sc[4];
#pragma unroll
            for (int mk = 0; mk < 4; mk++) {
                Sc[mk] = frag_cd{0.f, 0.f, 0.f, 0.f};
#pragma unroll
                for (int ks = 0; ks < 2; ks++)
                    Sc[mk] = __builtin_amdgcn_mfma_f32_16x16x32_bf16(
                        ka[mk][ks], qf[ks], Sc[mk], 0, 0, 0);
            }
            // S^T C-layout: col(r16)=q, row(quad*4+rg in mk-tile)=key.
            // Scores arrive in log2-domain (KSCALE pre-folded into Q).
            const int qg = qwave + r16;
            float mx = -1e30f;
#pragma unroll
            for (int mk = 0; mk < 4; mk++)
#pragma unroll
                for (int rg = 0; rg < 4; rg++) {
                    float sv = Sc[mk][rg];
                    if (domask) {
                        const int keyg = k0 + mk * 16 + quad * 4 + rg;
                        sv = (keyg <= qg) ? sv : -1e30f;
                    }
                    Sc[mk][rg] = sv;
                    mx = fmaxf(mx, sv);
                }
            mx = fmaxf(mx, __shfl_xor(mx, 16, 64));
            mx = fmaxf(mx, __shfl_xor(mx, 32, 64));
            const float mnew  = fmaxf(mrun, mx);
            const float alpha = __builtin_amdgcn_exp2f(mrun - mnew);
            mrun = mnew;
            float rs = 0.f;
#pragma unroll
            for (int mk = 0; mk < 4; mk++)
#pragma unroll
                for (int rg = 0; rg < 4; rg++) {
                    const float pv = __builtin_amdgcn_exp2f(Sc[mk][rg] - mnew);
                    Sc[mk][rg] = pv;
                    rs += pv;
                }
            rs += __shfl_xor(rs, 16, 64);
            rs += __shfl_xor(rs, 32, 64);
            lrun = lrun * alpha + rs;

            // packed P write: 4 consecutive keys/lane, granule-XOR swizzle (b64 floor)
            const int qrow = wave * 16 + r16;
#pragma unroll
            for (int mk = 0; mk < 4; mk++) {
                __align__(8) bf16 t4[4];
#pragma unroll
                for (int rg = 0; rg < 4; rg++) t4[rg] = __float2bfloat16(Sc[mk][rg]);
                const int g = (mk * 4 + quad) ^ r16;
                *(ull*)&Ps[qrow * 64 + g * 4] = *(const ull*)t4;
            }
            // rescale O^T: col=q=r16 matches alpha's index — direct multiply
#pragma unroll
            for (int nd = 0; nd < 4; nd++)
#pragma unroll
                for (int rg = 0; rg < 4; rg++) Oacc[nd][rg] *= alpha;

            // no barrier: Ps rows wave-private; per-wave LDS ops are in-order

            // PV (transposed): O^T[d][q] += Vt(d rows) x P(q rows)
            frag_ab pa[2], vb[4][2];
#pragma unroll
            for (int ks = 0; ks < 2; ks++) {
                const int gb = ks * 8 + quad * 2;
                union { ull u[2]; frag_ab f; } t;
                t.u[0] = *(const ull*)&Ps[qrow * 64 + ((gb    ) ^ r16) * 4];
                t.u[1] = *(const ull*)&Ps[qrow * 64 + ((gb + 1) ^ r16) * 4];
                pa[ks] = t.f;
            }
#pragma unroll
            for (int nd = 0; nd < 4; nd++) {
                const int row = nd * 16 + r16;
#pragma unroll
                for (int ks = 0; ks < 2; ks++)
                    vb[nd][ks] = *(const frag_ab*)&Vt[cur][row * 64 + (((ks * 4 + quad) ^ (row & 7)) * 8)];
            }
#pragma unroll
            for (int nd = 0; nd < 4; nd++)
#pragma unroll
                for (int ks = 0; ks < 2; ks++)
                    Oacc[nd] = __builtin_amdgcn_mfma_f32_16x16x32_bf16(
                        vb[nd][ks], pa[ks], Oacc[nd], 0, 0, 0);
        }

        __syncthreads();   // joins: prefetch complete + all waves done with cur bufs
    }

    // epilogue: Ctx[q][d] = O^T[d][q] / l — lane holds 4 consecutive d -> packed b64
    {
        const float invl = 1.f / lrun;
        const int qg = qwave + r16;
#pragma unroll
        for (int nd = 0; nd < 4; nd++) {
            __align__(8) bf16 t4[4];
#pragma unroll
            for (int rg = 0; rg < 4; rg++)
                t4[rg] = __float2bfloat16(Oacc[nd][rg] * invl);
            *(ull*)(Ctx + base + (size_t)qg * D + nd * 16 + quad * 4) = *(const ull*)t4;
        }
    }
}

// ---------- output projection, 64x128 tiles, single-barrier dbuf K-loop
__global__ __launch_bounds__(256) void gemm_out64(const bf16* __restrict__ A, const bf16* __restrict__ Bt,
                                                  const float* __restrict__ bias, float* __restrict__ Out) {
    __shared__ __align__(16) bf16 As[2][64 * BK];
    __shared__ __align__(16) bf16 Bs[2][128 * BK];
    const int tid = threadIdx.x, wave = tid >> 6, lane = tid & 63;
    const int r16 = lane & 15, quad = lane >> 4;
    const int row0 = blockIdx.y * 64;
    const int col0 = blockIdx.x * 128;
    const int wm = (wave & 1) * 32, wn = (wave >> 1) * 64;

    frag_cd acc[2][4];
#pragma unroll
    for (int mt = 0; mt < 2; mt++)
#pragma unroll
        for (int nt = 0; nt < 4; nt++) acc[mt][nt] = frag_cd{0.f, 0.f, 0.f, 0.f};

#pragma unroll
    for (int j = 0; j < 2; j++) {
        const int s = wave * 128 + j * 64 + lane;
        const int r = s >> 3, c = (s ^ r) & 7;
        gload_lds16(A + (size_t)(row0 + r) * D + c * 8, &As[0][(wave * 128 + j * 64) * 8]);
    }
#pragma unroll
    for (int j = 0; j < 4; j++) {
        const int s = wave * 256 + j * 64 + lane;
        const int r = s >> 3, c = (s ^ r) & 7;
        gload_lds16(Bt + (size_t)(col0 + r) * D + c * 8, &Bs[0][(wave * 256 + j * 64) * 8]);
    }
    __syncthreads();

    for (int kt = 0; kt < D / BK; kt++) {
        const int cur = kt & 1;
        if (kt + 1 < D / BK) {
            const int kn = (kt + 1) * BK;
#pragma unroll
            for (int j = 0; j < 2; j++) {
                const int s = wave * 128 + j * 64 + lane;
                const int r = s >> 3, c = (s ^ r) & 7;
                gload_lds16(A + (size_t)(row0 + r) * D + kn + c * 8,
                            &As[cur ^ 1][(wave * 128 + j * 64) * 8]);
            }
#pragma unroll
            for (int j = 0; j < 4; j++) {
                const int s = wave * 256 + j * 64 + lane;
                const int r = s >> 3, c = (s ^ r) & 7;
                gload_lds16(Bt + (size_t)(col0 + r) * D + kn + c * 8,
                            &Bs[cur ^ 1][(wave * 256 + j * 64) * 8]);
            }
        }

        frag_ab af[2][2], bf[4][2];
#pragma unroll
        for (int mt = 0; mt < 2; mt++) {
            const int row = wm + mt * 16 + r16;
#pragma unroll
            for (int ks = 0; ks < 2; ks++)
                af[mt][ks] = *(const frag_ab*)&As[cur][row * 64 + (((ks * 4 + quad) ^ (row & 7)) * 8)];
        }
#pragma unroll
        for (int nt = 0; nt < 4; nt++) {
            const int row = wn + nt * 16 + r16;
#pragma unroll
            for (int ks = 0; ks < 2; ks++)
                bf[nt][ks] = *(const frag_ab*)&Bs[cur][row * 64 + (((ks * 4 + quad) ^ (row & 7)) * 8)];
        }
#pragma unroll
        for (int mt = 0; mt < 2; mt++)
#pragma unroll
            for (int nt = 0; nt < 4; nt++)
#pragma unroll
                for (int ks = 0; ks < 2; ks++)
                    acc[mt][nt] = __builtin_amdgcn_mfma_f32_16x16x32_bf16(
                        af[mt][ks], bf[nt][ks], acc[mt][nt], 0, 0, 0);

        __syncthreads();
    }

#pragma unroll
    for (int mt = 0; mt < 2; mt++)
#pragma unroll
        for (int nt = 0; nt < 4; nt++) {
            const int col = col0 + wn + nt * 16 + r16;
            const float bv = bias[col];
#pragma unroll
            for (int rg = 0; rg < 4; rg++) {
                const int row = row0 + wm + mt * 16 + quad * 4 + rg;
                Out[(size_t)row * D + col] = acc[mt][nt][rg] + bv;
            }
        }
}

extern "C" void kernel_launch(void* const* d_in, const int* in_sizes, int n_in,
                              void* d_out, int out_size, void* d_ws, size_t ws_size,
                              hipStream_t stream) {
    const float* x  = (const float*)d_in[0];
    const float* Wq = (const float*)d_in[1];
    const float* Wk = (const float*)d_in[2];
    const float* Wv = (const float*)d_in[3];
    const float* Wo = (const float*)d_in[4];
    const float* bo = (const float*)d_in[5];
    float* out = (float*)d_out;

    bf16* xb    = (bf16*)d_ws;                 // [4096][1024]
    bf16* WqkvT = xb    + (size_t)M * D;       // [3072][1024] (WqT|WkT|WvT)
    bf16* WoT   = WqkvT + (size_t)3 * D * D;   // [1024][1024]
    bf16* Qb    = WoT   + (size_t)D * D;       // [B,S,D] (pre-scaled by KSCALE)
    bf16* Kb    = Qb    + (size_t)M * D;       // [B,S,D]
    bf16* Vt_g  = Kb    + (size_t)M * D;       // [32][64][2048]
    bf16* Ctxb  = Vt_g  + (size_t)M * D;       // [B,S,D]

    prep<<<dim3(32, 32, 5), 256, 0, stream>>>(x, xb, Wq, Wk, Wv, Wo,
                                              WqkvT, WqkvT + (size_t)D * D,
                                              WqkvT + (size_t)2 * D * D, WoT);
    gemm_qkv_all<<<dim3(24, 32), 256, 0, stream>>>(xb, WqkvT, Qb, Kb, Vt_g);
    attn_mfma<<<dim3(B * NH, S / BQ), 256, 0, stream>>>(Qb, Kb, Vt_g, Ctxb);
    gemm_out64<<<dim3(8, 64), 256, 0, stream>>>(Ctxb, WoT, bo, out);
}